// Round 2
// 432.119 us; speedup vs baseline: 1.0142x; 1.0142x over previous
//
#include <hip/hip_runtime.h>

// ===========================================================================
// ViewGCNEncoder r17b (resubmit of r17; prior round was an infra failure) =
// r16 + (1) skip x->frag conversion when inputs are bf16 (GEMM layer-1 reads
// A fragments directly from row-major x: frag layout is 8 contiguous
// row-major elems per lane), (2) XCD-partitioned CSR scatter (block b scans
// stripe b>>3, commits only rows of partition b&7 -> all stores to an ecv
// line come from one XCD's L2 -> full-line writeback, kills ~51MB write
// amplification), (3) vectorized u8/bf16 mask loads in SpMM.
// 12 launches. Workspace ~84 MB (<=110 MB proven safe).
// ===========================================================================

typedef unsigned short ushort_t;
typedef __attribute__((ext_vector_type(8))) short bf16x8;   // 8 bf16 = 4 VGPRs
typedef __attribute__((ext_vector_type(4))) float f32x4;
typedef __attribute__((ext_vector_type(2))) unsigned int u32x2;
typedef __attribute__((ext_vector_type(4))) unsigned int u32x4;

__device__ __forceinline__ float bf2f(ushort_t u) {
  return __uint_as_float(((unsigned int)u) << 16);
}
__device__ __forceinline__ ushort_t f2bf(float f) {
  unsigned int u = __float_as_uint(f);
  return (ushort_t)((u + 0x7FFFu + ((u >> 16) & 1u)) >> 16);  // RNE
}
__device__ __forceinline__ float read_f(const void* p, int fm, size_t i) {
  return fm ? bf2f(((const ushort_t*)p)[i]) : ((const float*)p)[i];
}

// fragment-order offset: tile-major 16-row tiles; within tile kc-chunk(32 k)
// then lane-linear (lane = (m&15)+16*((k>>3)&3), 8 elems each).
__device__ __forceinline__ size_t frag_off(int m, int k, int K) {
  return (size_t)(m >> 4) * 16 * K + ((size_t)(k >> 5) << 9) +
         (((k >> 3) & 3) << 7) + ((m & 15) << 3) + (k & 7);
}

__device__ __forceinline__ bool mask_keep(const void* mask, int mm, size_t o) {
  switch (mm) {
    case 1:  return ((const int*)mask)[o] != 0;
    case 2:  return ((const unsigned int*)mask)[o] != 0u;
    case 3:  return ((const ushort_t*)mask)[o] != 0;
    default: return ((const unsigned char*)mask)[o] != 0;
  }
}

// ---------------- prep: dtype sniff (blocks 0-2) + zero cnt/fill (blocks 3+)
__global__ void prep_kernel(const void* __restrict__ x,
                            const void* __restrict__ m1,
                            const void* __restrict__ m2,
                            int* __restrict__ modes,
                            int* __restrict__ zero_region, int zn) {
  if (blockIdx.x == 0) {
    __shared__ int bfok;
    if (threadIdx.x == 0) bfok = 1;
    __syncthreads();
    for (int i = threadIdx.x; i < 8192; i += blockDim.x) {
      ushort_t h = ((const ushort_t*)x)[i];
      int e = (h >> 7) & 0xFF;
      if (!(h == 0 || (e >= 95 && e <= 133))) atomicAnd(&bfok, 0);
    }
    __syncthreads();
    if (threadIdx.x == 0) modes[0] = bfok;   // 1=bf16, 0=f32
  } else if (blockIdx.x <= 2) {
    const void* p = (blockIdx.x == 1) ? m1 : m2;
    __shared__ int ok[4];  // [i32, f32, bf16, u8]
    if (threadIdx.x < 4) ok[threadIdx.x] = 1;
    __syncthreads();
    for (int i = threadIdx.x; i < 4096; i += blockDim.x) {
      unsigned int w = ((const unsigned int*)p)[i];
      if (!(w == 0u || w == 1u)) atomicAnd(&ok[0], 0);
      if (!(w == 0u || w == 0x3F800000u)) atomicAnd(&ok[1], 0);
      unsigned int h16 = w >> 16, l16 = w & 0xFFFFu;
      if (!((h16 == 0u || h16 == 0x3F80u) && (l16 == 0u || l16 == 0x3F80u)))
        atomicAnd(&ok[2], 0);
      if (((w | (w >> 8) | (w >> 16) | (w >> 24)) & 0xFEu) != 0u) atomicAnd(&ok[3], 0);
    }
    __syncthreads();
    if (threadIdx.x == 0)
      modes[blockIdx.x] = ok[0] ? 1 : (ok[1] ? 2 : (ok[2] ? 3 : 0));
  } else {
    int i = (blockIdx.x - 3) * blockDim.x + threadIdx.x;
    int stride = (gridDim.x - 3) * blockDim.x;
    for (; i < zn; i += stride) zero_region[i] = 0;
  }
}

// ---------------- CSR build (frozen) ----------------
__global__ void hist_kernel(const int* __restrict__ rows, int* __restrict__ cnt, int E) {
  int i = blockIdx.x * blockDim.x + threadIdx.x;
  int stride = gridDim.x * blockDim.x;
  for (; i < E; i += stride) atomicAdd(&cnt[rows[i]], 1);
}

__global__ void scan_part_kernel(const int* __restrict__ cnt, int* __restrict__ part, int n) {
  __shared__ int s[256];
  int i = blockIdx.x * 256 + threadIdx.x;
  s[threadIdx.x] = (i < n) ? cnt[i] : 0;
  __syncthreads();
  for (int off = 128; off > 0; off >>= 1) {
    if (threadIdx.x < off) s[threadIdx.x] += s[threadIdx.x + off];
    __syncthreads();
  }
  if (threadIdx.x == 0) part[blockIdx.x] = s[0];
}

__global__ __launch_bounds__(1024) void scan_top_kernel(int* __restrict__ part, int P) {
  __shared__ int s[1024];
  int t = threadIdx.x;
  int v = (t < P) ? part[t] : 0;
  s[t] = v;
  __syncthreads();
  for (int off = 1; off < 1024; off <<= 1) {
    int x = s[t];
    int y = (t >= off) ? s[t - off] : 0;
    __syncthreads();
    s[t] = x + y;
    __syncthreads();
  }
  if (t < P) part[t] = s[t] - v;   // exclusive
}

__global__ void scan_apply_kernel(const int* __restrict__ cnt, const int* __restrict__ part,
                                  int* __restrict__ row_start, int n) {
  __shared__ int s[256];
  int base = part[blockIdx.x];
  int i = blockIdx.x * 256 + threadIdx.x;
  int v = (i < n) ? cnt[i] : 0;
  s[threadIdx.x] = v;
  __syncthreads();
  for (int off = 1; off < 256; off <<= 1) {
    int x = s[threadIdx.x];
    int y = (threadIdx.x >= off) ? s[threadIdx.x - off] : 0;
    __syncthreads();
    s[threadIdx.x] = x + y;
    __syncthreads();
  }
  if (i < n) row_start[i] = base + s[threadIdx.x] - v;
  if (i == n - 1) row_start[n] = base + s[threadIdx.x];
}

// ---------------- fused scatter (blocks 0..1023) + convert (blocks 1024+) ---
// Scatter is XCD-partitioned: block b scans edge stripe (b>>3), commits only
// edges whose destination row lies in partition (b&7). blockIdx%8 == XCD on
// MI355X, so each ecv cache line is written from exactly one XCD's L2 ->
// full-line writeback instead of 8B-partial-dirty flushes.
__global__ void scatter_convert_kernel(
    const int* __restrict__ rows, const int* __restrict__ cols,
    const void* __restrict__ vals, const int* __restrict__ fm_p,
    const int* __restrict__ row_start, int* __restrict__ fill,
    int2* __restrict__ ecv, int E,
    const void* __restrict__ W1, const void* __restrict__ W2, const void* __restrict__ W3,
    const void* __restrict__ b1, const void* __restrict__ b2, const void* __restrict__ b3,
    const void* __restrict__ x,
    ushort_t* __restrict__ whi, ushort_t* __restrict__ wlo,
    float* __restrict__ biasf, ushort_t* __restrict__ xbf,
    int n1, int n2, int n3, int h1, int h2, int h3, int K1, int K2, int K3,
    int nx, int Nrows) {
  int fm = *fm_p;
  if (blockIdx.x < 1024) {
    // --- partitioned scatter: packed (col, val) edge stream ---
    int part = blockIdx.x & 7;              // XCD heuristic (bid % 8)
    int stripe = blockIdx.x >> 3;           // 128 stripes over E
    float pscale = 8.0f / (float)Nrows;     // monotone, deterministic
    int i = stripe * blockDim.x + threadIdx.x;
    int stride = 128 * blockDim.x;
    for (; i < E; i += stride) {
      int r = rows[i];
      int p = (int)((float)r * pscale);
      p = (p > 7) ? 7 : p;
      if (p != part) continue;
      int pos = atomicAdd(&fill[r], 1);
      int idx = row_start[r] + pos;
      ecv[idx] = make_int2(cols[i], __float_as_int(read_f(vals, fm, i)));
    }
  } else {
    // --- convert: W split + bias (+ x->bf16 frag only when x is f32) ---
    int wtot = n1 + n2 + n3;
    int btot = h1 + h2 + h3;
    int nx4 = (fm == 1) ? 0 : nx / 4;       // bf16 x: GEMM reads x directly
    int total = wtot + btot + nx4;
    int i = (blockIdx.x - 1024) * blockDim.x + threadIdx.x;
    int stride = (gridDim.x - 1024) * blockDim.x;
    for (; i < total; i += stride) {
      if (i < wtot) {
        const void* src; int j, K; size_t base;
        if (i < n1) { src = W1; j = i; K = K1; base = 0; }
        else if (i < n1 + n2) { src = W2; j = i - n1; K = K2; base = n1; }
        else { src = W3; j = i - n1 - n2; K = K3; base = (size_t)n1 + n2; }
        int n = j / K, k = j - n * K;
        float v = read_f(src, fm, j);
        ushort_t h = f2bf(v);
        size_t o = base + frag_off(n, k, K);
        whi[o] = h;
        wlo[o] = f2bf(v - bf2f(h));
      } else if (i < wtot + btot) {
        int k = i - wtot;
        const void* src; int j;
        if (k < h1) { src = b1; j = k; }
        else if (k < h1 + h2) { src = b2; j = k - h1; }
        else { src = b3; j = k - h1 - h2; }
        biasf[k] = read_f(src, fm, j);
      } else {
        int k4 = i - wtot - btot;          // 4 consecutive elems of x (f32)
        int m = k4 / (K1 / 4);
        int k0 = (k4 - m * (K1 / 4)) * 4;
        f32x4 v = ((const f32x4*)x)[k4];
        ushort_t p0 = f2bf(v[0]), p1 = f2bf(v[1]), p2 = f2bf(v[2]), p3 = f2bf(v[3]);
        size_t o = frag_off(m, k0, K1);
        *(u32x2*)(xbf + o) = (u32x2){
            (unsigned int)p0 | ((unsigned int)p1 << 16),
            (unsigned int)p2 | ((unsigned int)p3 << 16)};
      }
    }
  }
}

// ---------------- GEMM: fragment-ordered A and W (frozen r15 core) ----------
// A-fragment for one lane (mr=lane&15, quad=lane>>4) of kc-chunk kc is the 8
// contiguous row-major elems A[m0+mr][kc*32+quad*8 .. +8] -> when x is bf16
// row-major we can load fragments straight from x (rowA path).
template<int KC>
__device__ __forceinline__ void load_afrag(const ushort_t* __restrict__ A,
                                           const ushort_t* __restrict__ Xrow,
                                           bool rowA, int mtile, int K,
                                           int lane, int mr, int quad, int M,
                                           bf16x8* dst) {
  if (rowA) {
    int rr = mtile * 16 + mr;
    if (rr >= M) rr = M - 1;
    const ushort_t* ap = Xrow + (size_t)rr * K + quad * 8;
#pragma unroll
    for (int kc = 0; kc < KC; ++kc) dst[kc] = *(const bf16x8*)(ap + kc * 32);
  } else {
    const ushort_t* ap = A + (size_t)mtile * 16 * K + lane * 8;
#pragma unroll
    for (int kc = 0; kc < KC; ++kc) dst[kc] = *(const bf16x8*)(ap + kc * 512);
  }
}

template<int KC>
__global__ __launch_bounds__(256) void gemm_breg_kernel(
    const ushort_t* __restrict__ A,
    const ushort_t* __restrict__ Xrow, const int* __restrict__ fm_p,
    const ushort_t* __restrict__ Whi, const ushort_t* __restrict__ Wlo,
    const float* __restrict__ bias, ushort_t* __restrict__ g, int ldg,
    int M, int nct) {
  const int K = KC * 32;
  int wave = threadIdx.x >> 6, lane = threadIdx.x & 63;
  int gw = blockIdx.x * 4 + wave;
  int NW = gridDim.x * 4;
  int mr = lane & 15, quad = lane >> 4;
  int ct = gw % nct;
  int nrt = (M + 15) >> 4;
  int ntasks = nct * nrt;
  if (gw >= ntasks) return;

  bool rowA = (Xrow != nullptr) && (*fm_p != 0);

  bf16x8 wh[KC], wl[KC];
  {
    const ushort_t* wp = Whi + (size_t)ct * 16 * K + lane * 8;
    const ushort_t* wq = Wlo + (size_t)ct * 16 * K + lane * 8;
#pragma unroll
    for (int kc = 0; kc < KC; ++kc) {
      wh[kc] = *(const bf16x8*)(wp + kc * 512);
      wl[kc] = *(const bf16x8*)(wq + kc * 512);
    }
  }
  int col = ct * 16 + mr;
  float bv = bias[col];

  int task = gw;
  bf16x8 af[KC];
  load_afrag<KC>(A, Xrow, rowA, task / nct, K, lane, mr, quad, M, af);

#pragma unroll 1
  for (;;) {
    int next = task + NW;
    bool has_next = next < ntasks;
    bf16x8 afn[KC];
    if (has_next)
      load_afrag<KC>(A, Xrow, rowA, next / nct, K, lane, mr, quad, M, afn);

    f32x4 acc[4];
#pragma unroll
    for (int t = 0; t < 4; ++t) acc[t] = (f32x4){0.f, 0.f, 0.f, 0.f};
#pragma unroll
    for (int kc = 0; kc < KC; ++kc) {
      acc[(2 * kc) & 3] = __builtin_amdgcn_mfma_f32_16x16x32_bf16(af[kc], wh[kc], acc[(2 * kc) & 3], 0, 0, 0);
      acc[(2 * kc + 1) & 3] = __builtin_amdgcn_mfma_f32_16x16x32_bf16(af[kc], wl[kc], acc[(2 * kc + 1) & 3], 0, 0, 0);
    }
    int m0 = (task / nct) * 16;
#pragma unroll
    for (int r = 0; r < 4; ++r) {
      int row = m0 + quad * 4 + r;
      float s = ((acc[0][r] + acc[1][r]) + (acc[2][r] + acc[3][r])) + bv;
      if (row < M) g[(size_t)row * ldg + col] = f2bf(s);
    }
    if (!has_next) break;
#pragma unroll
    for (int kc = 0; kc < KC; ++kc) af[kc] = afn[kc];
    task = next;
  }
}

// ---------------- SpMM v8: gathers (r14) + LDS-staged frag flush ------------
// out[r,f] = sum_e val[e]*G[col[e],f].  One wave per row, VEC elems/lane.
// MODE 1: leaky+mask (vectorized mask load for all dtypes) -> LDS stage ->
//         coalesced 64B-line frag-order flush (4 rows/block = full lines).
// MODE 0: plain -> f32 row-major (final d_out).
template<int MODE, int VEC>
__global__ __launch_bounds__(256) void spmm8_kernel(
    const int* __restrict__ row_start, const int2* __restrict__ ecv,
    const ushort_t* __restrict__ G, int D,
    const void* __restrict__ mask, const int* __restrict__ mmode_p,
    void* __restrict__ outp, int N) {
  __shared__ ushort_t stage[1024];         // 4 rows x up to 256 cols
  int wave = threadIdx.x >> 6, lane = threadIdx.x & 63;
  int r = blockIdx.x * 4 + wave;
  bool active = r < N;
  float a[VEC];
#pragma unroll
  for (int q = 0; q < VEC; ++q) a[q] = 0.f;
  int f0 = lane * VEC;

  if (active) {
    int e  = __builtin_amdgcn_readfirstlane(row_start[r]);
    int e1 = __builtin_amdgcn_readfirstlane(row_start[r + 1]);
    for (; e + 8 <= e1; e += 8) {
      int2 cv[8];
#pragma unroll
      for (int j = 0; j < 8; ++j) cv[j] = ecv[e + j];
      if (VEC == 4) {
        u32x2 gg[8];
#pragma unroll
        for (int j = 0; j < 8; ++j)
          gg[j] = *(const u32x2*)(G + (size_t)cv[j].x * D + f0);
#pragma unroll
        for (int j = 0; j < 8; ++j) {
          float v = __int_as_float(cv[j].y);
          a[0] += v * bf2f((ushort_t)gg[j][0]);
          a[1] += v * bf2f((ushort_t)(gg[j][0] >> 16));
          a[2] += v * bf2f((ushort_t)gg[j][1]);
          a[3] += v * bf2f((ushort_t)(gg[j][1] >> 16));
        }
      } else if (VEC == 2) {
        unsigned int gg[8];
#pragma unroll
        for (int j = 0; j < 8; ++j)
          gg[j] = *(const unsigned int*)(G + (size_t)cv[j].x * D + f0);
#pragma unroll
        for (int j = 0; j < 8; ++j) {
          float v = __int_as_float(cv[j].y);
          a[0] += v * bf2f((ushort_t)gg[j]);
          a[1] += v * bf2f((ushort_t)(gg[j] >> 16));
        }
      } else {
        ushort_t h[8];
#pragma unroll
        for (int j = 0; j < 8; ++j) h[j] = G[(size_t)cv[j].x * D + f0];
#pragma unroll
        for (int j = 0; j < 8; ++j) a[0] += __int_as_float(cv[j].y) * bf2f(h[j]);
      }
    }
    if (e < e1) {
      int idx[8]; float v[8];
#pragma unroll
      for (int j = 0; j < 8; ++j) {
        int ee = e + j;
        bool ok = ee < e1;
        int2 cv = ecv[ok ? ee : e1 - 1];
        idx[j] = cv.x;
        v[j] = ok ? __int_as_float(cv.y) : 0.f;
      }
      if (VEC == 4) {
        u32x2 gg[8];
#pragma unroll
        for (int j = 0; j < 8; ++j)
          gg[j] = *(const u32x2*)(G + (size_t)idx[j] * D + f0);
#pragma unroll
        for (int j = 0; j < 8; ++j) {
          a[0] += v[j] * bf2f((ushort_t)gg[j][0]);
          a[1] += v[j] * bf2f((ushort_t)(gg[j][0] >> 16));
          a[2] += v[j] * bf2f((ushort_t)gg[j][1]);
          a[3] += v[j] * bf2f((ushort_t)(gg[j][1] >> 16));
        }
      } else if (VEC == 2) {
        unsigned int gg[8];
#pragma unroll
        for (int j = 0; j < 8; ++j)
          gg[j] = *(const unsigned int*)(G + (size_t)idx[j] * D + f0);
#pragma unroll
        for (int j = 0; j < 8; ++j) {
          a[0] += v[j] * bf2f((ushort_t)gg[j]);
          a[1] += v[j] * bf2f((ushort_t)(gg[j] >> 16));
        }
      } else {
        ushort_t h[8];
#pragma unroll
        for (int j = 0; j < 8; ++j) h[j] = G[(size_t)idx[j] * D + f0];
#pragma unroll
        for (int j = 0; j < 8; ++j) a[0] += v[j] * bf2f(h[j]);
      }
    }
  }

  if (MODE == 1) {
    if (active) {
      size_t om = (size_t)r * D + f0;      // mask is row-major
      int mm = *mmode_p;
      bool keep[VEC];
      if (mm == 1 || mm == 2) {            // 4B/elem: vector load
        if (VEC == 4) {
          u32x4 mv = *(const u32x4*)((const unsigned int*)mask + om);
#pragma unroll
          for (int q = 0; q < VEC; ++q) keep[q] = mv[q] != 0u;
        } else if (VEC == 2) {
          u32x2 mv = *(const u32x2*)((const unsigned int*)mask + om);
#pragma unroll
          for (int q = 0; q < VEC; ++q) keep[q] = mv[q] != 0u;
        } else {
          keep[0] = ((const unsigned int*)mask)[om] != 0u;
        }
      } else if (mm == 3) {                // bf16: vector load
        if (VEC == 4) {
          u32x2 mv = *(const u32x2*)((const ushort_t*)mask + om);
          keep[0] = (mv[0] & 0xFFFFu) != 0u; keep[1] = (mv[0] >> 16) != 0u;
          keep[2] = (mv[1] & 0xFFFFu) != 0u; keep[3] = (mv[1] >> 16) != 0u;
        } else if (VEC == 2) {
          unsigned int mv = *(const unsigned int*)((const ushort_t*)mask + om);
          keep[0] = (mv & 0xFFFFu) != 0u; keep[1] = (mv >> 16) != 0u;
        } else {
          keep[0] = ((const ushort_t*)mask)[om] != 0;
        }
      } else {                             // u8: vector load
        if (VEC == 4) {
          unsigned int mv = *(const unsigned int*)((const unsigned char*)mask + om);
          keep[0] = (mv & 0xFFu) != 0u;        keep[1] = ((mv >> 8) & 0xFFu) != 0u;
          keep[2] = ((mv >> 16) & 0xFFu) != 0u; keep[3] = (mv >> 24) != 0u;
        } else if (VEC == 2) {
          unsigned int mv = *(const unsigned short*)((const unsigned char*)mask + om);
          keep[0] = (mv & 0xFFu) != 0u; keep[1] = ((mv >> 8) & 0xFFu) != 0u;
        } else {
          keep[0] = ((const unsigned char*)mask)[om] != 0;
        }
      }
#pragma unroll
      for (int q = 0; q < VEC; ++q) {
        float t = a[q];
        t = (t >= 0.f) ? t : 0.2f * t;             // leaky relu 0.2
        t = keep[q] ? t * 1.25f : 0.f;             // keep = 1/(1-0.2)
        stage[wave * D + f0 + q] = f2bf(t);
      }
    }
    __syncthreads();
    // flush: D threads, one 8B (4-elem) piece each; 64B line = 4 rows' chunks
    if (threadIdx.x < D) {
      int g = threadIdx.x >> 3, s = threadIdx.x & 7;   // group, sub
      int kc = g >> 2, quad = g & 3;
      int sr = s >> 1;                                  // source row in block
      int r0 = blockIdx.x * 4;
      if (r0 + sr < N) {
        int kk = kc * 32 + quad * 8 + (s & 1) * 4;
        size_t dst = (size_t)(r0 >> 4) * 16 * D + ((size_t)kc << 9) +
                     (quad << 7) + ((r0 & 15) << 3) + s * 4;
        *(u32x2*)((ushort_t*)outp + dst) = *(const u32x2*)(stage + sr * D + kk);
      }
    }
  } else {
    if (active) {
      size_t o = (size_t)r * D + f0;
#pragma unroll
      for (int q = 0; q < VEC; ++q) ((float*)outp)[o + q] = a[q];
    }
  }
}

// ---------------- launch ----------------
extern "C" void kernel_launch(void* const* d_in, const int* in_sizes, int n_in,
                              void* d_out, int out_size, void* d_ws, size_t ws_size,
                              hipStream_t stream) {
  const void* x     = d_in[0];
  const int*  rows  = (const int*)d_in[1];
  const int*  cols  = (const int*)d_in[2];
  const void* vals  = d_in[3];
  const void* W1    = d_in[4];
  const void* b1    = d_in[5];
  const void* W2    = d_in[6];
  const void* b2    = d_in[7];
  const void* W3    = d_in[8];
  const void* b3    = d_in[9];
  const void* mask1 = d_in[10];
  const void* mask2 = d_in[11];

  const int H1  = in_sizes[5];            // 256
  const int H2  = in_sizes[7];            // 128
  const int OUT = in_sizes[9];            // 64
  const int IN  = in_sizes[4] / H1;       // 256
  const int N   = in_sizes[0] / IN;       // 50000
  const int E   = in_sizes[1];            // 800000
  const int W1n = in_sizes[4], W2n = in_sizes[6], W3n = in_sizes[8];
  const int Np  = ((N + 15) / 16) * 16;

  char* ws = (char*)d_ws;
  size_t off = 0;
  auto alloc = [&](size_t bytes) -> void* {
    void* p = ws + off;
    off = (off + bytes + 255) & ~(size_t)255;
    return p;
  };
  int*      modes     = (int*)alloc(4 * 4);
  int*      row_start = (int*)alloc((size_t)(N + 1) * 4);
  int*      cnt       = (int*)alloc((size_t)N * 8);   // [cnt | fill]
  int*      part      = (int*)alloc(1024 * 4);
  int2*     ecv       = (int2*)alloc((size_t)E * 8);
  ushort_t* whi       = (ushort_t*)alloc((size_t)(W1n + W2n + W3n) * 2);
  ushort_t* wlo       = (ushort_t*)alloc((size_t)(W1n + W2n + W3n) * 2);
  float*    biasf     = (float*)alloc((size_t)(H1 + H2 + OUT) * 4);
  ushort_t* bufA      = (ushort_t*)alloc((size_t)Np * H1 * 2);   // frag
  ushort_t* bufB      = (ushort_t*)alloc((size_t)Np * H1 * 2);   // row-major G
  ushort_t* bufC      = (ushort_t*)alloc((size_t)Np * H1 * 2);   // frag
  // total ~84 MB (<=110 MB proven safe in r3)

  int* fmode = modes;
  int* mm1   = modes + 1;
  int* mm2   = modes + 2;
  int* fill  = cnt + N;
  ushort_t* w1hi = whi,             *w1lo = wlo;
  ushort_t* w2hi = whi + W1n,       *w2lo = wlo + W1n;
  ushort_t* w3hi = whi + W1n + W2n, *w3lo = wlo + W1n + W2n;

  // prep: sniff (3 blocks) + zero cnt/fill
  prep_kernel<<<259, 256, 0, stream>>>(x, mask1, mask2, modes, cnt, 2 * N);

  // CSR build with parallel scan
  const int P = (N + 255) / 256;
  hist_kernel<<<1024, 256, 0, stream>>>(rows, cnt, E);
  scan_part_kernel<<<P, 256, 0, stream>>>(cnt, part, N);
  scan_top_kernel<<<1, 1024, 0, stream>>>(part, P);
  scan_apply_kernel<<<P, 256, 0, stream>>>(cnt, part, row_start, N);

  // fused: partitioned scatter (1024 blocks) + conversions (2048 blocks)
  scatter_convert_kernel<<<3072, 256, 0, stream>>>(
      rows, cols, vals, fmode, row_start, fill, ecv, E,
      W1, W2, W3, b1, b2, b3, x, whi, wlo, biasf, bufA,
      W1n, W2n, W3n, H1, H2, OUT, IN, H1, H2, N * IN, N);

  const int GEMM_BLOCKS = 1024;            // 4096 waves; % {16,8,4} == 0
  int spmm_grid = (N + 3) / 4;

  // layer 1: GEMM(IN->H1, A = x row-major if bf16 else bufA frag)
  //          -> bufB row-major -> SpMM -> bufC frag
  gemm_breg_kernel<8><<<GEMM_BLOCKS, 256, 0, stream>>>(
      bufA, (const ushort_t*)x, fmode, w1hi, w1lo, biasf, bufB, H1, N, H1 / 16);
  spmm8_kernel<1, 4><<<spmm_grid, 256, 0, stream>>>(
      row_start, ecv, bufB, H1, mask1, mm1, bufC, N);
  // layer 2: GEMM(H1->H2, A=bufC frag) -> bufB row-major -> SpMM -> bufA frag
  gemm_breg_kernel<8><<<GEMM_BLOCKS, 256, 0, stream>>>(
      bufC, nullptr, fmode, w2hi, w2lo, biasf + H1, bufB, H2, N, H2 / 16);
  spmm8_kernel<1, 2><<<spmm_grid, 256, 0, stream>>>(
      row_start, ecv, bufB, H2, mask2, mm2, bufA, N);
  // layer 3: GEMM(H2->OUT, A=bufA frag) -> bufB row-major -> SpMM -> f32 d_out
  gemm_breg_kernel<4><<<GEMM_BLOCKS, 256, 0, stream>>>(
      bufA, nullptr, fmode, w3hi, w3lo, biasf + H1 + H2, bufB, OUT, N, OUT / 16);
  spmm8_kernel<0, 1><<<spmm_grid, 256, 0, stream>>>(
      row_start, ecv, bufB, OUT, nullptr, fmode, d_out, N);
}